// Round 2
// baseline (454.271 us; speedup 1.0000x reference)
//
#include <hip/hip_runtime.h>

// ParallelTransport: out[e,c,:] = R(rho[e]) @ x[row[e], c, :]
// R = [[c,-s],[s,c]]; layout (...,C,2): consecutive f32 are (comp0,comp1).
// Dtypes (verified in prior session): x f32, edge_index int32 (harness-
// converted), rho f32, out f32.
//
// 8 threads/edge, each handling 2x 16B of the edge's 256B row.
// Access shape: thread k covers bytes [k*16, k*16+16) and [128+k*16, ...+16)
// so each instruction per 8-lane group writes/reads exactly one full 128B
// cache line.
//
// out (410 MB) is a pure write stream, never re-read -> nontemporal stores
// keep it from evicting x (12.8 MB, gather-reused ~32x) out of the 4 MB
// per-XCD L2s. row/rho are read-once streams -> nontemporal loads.
//
// NOTE: __builtin_nontemporal_* requires NATIVE clang vector types, not
// HIP_vector_type classes -> use ext_vector_type(4) float.

typedef float v4f __attribute__((ext_vector_type(4)));

__device__ __forceinline__ float2 rot_pair(float p0, float p1, float c, float s) {
    float2 y;
    y.x = fmaf(c, p0, -(s * p1));   // c*p0 - s*p1
    y.y = fmaf(s, p0,  c * p1);     // s*p0 + c*p1
    return y;
}

__global__ __launch_bounds__(256) void ParallelTransport_kernel(
    const float* __restrict__ x,      // (N, 32, 2) = N*64 f32
    const int*   __restrict__ row,    // edge_index[0], E int32
    const float* __restrict__ rho,    // E f32
    float*       __restrict__ out,    // (E, 32, 2) = E*64 f32
    int E)
{
    int t = blockIdx.x * blockDim.x + threadIdx.x;
    int e = t >> 3;          // edge
    int k = t & 7;           // 16B chunk index within a 128B half-row
    if (e >= E) return;

    int   r   = __builtin_nontemporal_load(row + e);
    float ang = __builtin_nontemporal_load(rho + e);
    float s, c;
    __sincosf(ang, &s, &c);

    // x row base: r*64 floats. a covers line 0 (bytes 0..127), b line 1.
    const float* srcf = x + ((size_t)r << 6) + (k << 2);
    v4f a = *reinterpret_cast<const v4f*>(srcf);        // cached: x is reused
    v4f b = *reinterpret_cast<const v4f*>(srcf + 32);

    float2 p0 = rot_pair(a.x, a.y, c, s);
    float2 p1 = rot_pair(a.z, a.w, c, s);
    float2 p2 = rot_pair(b.x, b.y, c, s);
    float2 p3 = rot_pair(b.z, b.w, c, s);

    float* dstf = out + ((size_t)e << 6) + (k << 2);
    v4f o0 = {p0.x, p0.y, p1.x, p1.y};
    v4f o1 = {p2.x, p2.y, p3.x, p3.y};
    __builtin_nontemporal_store(o0, reinterpret_cast<v4f*>(dstf));
    __builtin_nontemporal_store(o1, reinterpret_cast<v4f*>(dstf + 32));
}

extern "C" void kernel_launch(void* const* d_in, const int* in_sizes, int n_in,
                              void* d_out, int out_size, void* d_ws, size_t ws_size,
                              hipStream_t stream) {
    const float* x   = (const float*)d_in[0];
    const int*   ei  = (const int*)d_in[1];    // (2,E) int32; row = first E
    const float* rho = (const float*)d_in[2];
    float*       out = (float*)d_out;

    const int E = in_sizes[2];                 // rho element count
    const int threads = E * 8;
    const int block = 256;
    const int grid = (threads + block - 1) / block;

    ParallelTransport_kernel<<<grid, block, 0, stream>>>(x, ei, rho, out, E);
}